// Round 1
// baseline (167.420 us; speedup 1.0000x reference)
//
#include <hip/hip_runtime.h>

#define N_ELEM 95

__global__ void zbl_zero_kernel(float* __restrict__ out, int n) {
    int i = blockIdx.x * blockDim.x + threadIdx.x;
    if (i < n) out[i] = 0.0f;
}

__global__ __launch_bounds__(256) void zbl_edge_kernel(
    const int*   __restrict__ z,
    const float* __restrict__ dist,
    const int*   __restrict__ sender,
    const int*   __restrict__ receiver,
    const float* __restrict__ a_factor_p,
    const float* __restrict__ z_power_p,
    const float* __restrict__ coefs,
    const float* __restrict__ exps,
    const float* __restrict__ cradii,
    float*       __restrict__ out,
    int n_edges)
{
    __shared__ float s_pow[N_ELEM];   // Z^Z_power table (index by atomic number)
    __shared__ float s_cr[N_ELEM];    // covalent radii
    __shared__ float s_coef[4];
    __shared__ float s_exp[4];
    __shared__ float s_inv_pref;      // 1 / (a_factor * 0.529)

    const int tid = threadIdx.x;
    if (tid < N_ELEM) {
        float zp = z_power_p[0];
        s_pow[tid] = __powf((float)tid, zp);  // tid=0 unused (z >= 1)
        s_cr[tid]  = cradii[tid];
    }
    if (tid < 4) { s_coef[tid] = coefs[tid]; s_exp[tid] = exps[tid]; }
    if (tid == 0) s_inv_pref = 1.0f / (a_factor_p[0] * 0.529f);
    __syncthreads();

    const float inv_pref = s_inv_pref;
    const int n_vec   = n_edges >> 2;              // groups of 4 edges
    const int gstride = gridDim.x * blockDim.x;

    for (int i = blockIdx.x * blockDim.x + tid; i < n_vec; i += gstride) {
        const float4 d4 = reinterpret_cast<const float4*>(dist)[i];
        const int4   s4 = reinterpret_cast<const int4*>(sender)[i];
        const int4   r4 = reinterpret_cast<const int4*>(receiver)[i];

        float dd[4] = {d4.x, d4.y, d4.z, d4.w};
        int   ss[4] = {s4.x, s4.y, s4.z, s4.w};
        int   rr[4] = {r4.x, r4.y, r4.z, r4.w};

        #pragma unroll
        for (int k = 0; k < 4; ++k) {
            const float d  = dd[k];
            const int   zu = z[ss[k]];
            const int   zv = z[rr[k]];

            const float rmax = s_cr[zu] + s_cr[zv];
            const float t    = __fdividef(d, rmax);
            if (t < 1.0f) {
                const float roa = d * (s_pow[zu] + s_pow[zv]) * inv_pref;
                const float phi = s_coef[0] * __expf(-s_exp[0] * roa)
                                + s_coef[1] * __expf(-s_exp[1] * roa)
                                + s_coef[2] * __expf(-s_exp[2] * roa)
                                + s_coef[3] * __expf(-s_exp[3] * roa);
                const float v   = 14.3996f * (float)(zu * zv) * phi * __frcp_rn(d);
                const float t2  = t * t;
                const float t6  = t2 * t2 * t2;
                // p=6: 1 - 28 t^6 + 48 t^7 - 21 t^8
                const float env = 1.0f - t6 * (28.0f - 48.0f * t + 21.0f * t2);
                atomicAdd(&out[rr[k]], 0.5f * v * env);
            }
        }
    }

    // scalar tail (n_edges % 4)
    for (int i = (n_vec << 2) + blockIdx.x * blockDim.x + tid; i < n_edges; i += gstride) {
        const float d  = dist[i];
        const int   su = sender[i];
        const int   rv = receiver[i];
        const int   zu = z[su];
        const int   zv = z[rv];
        const float rmax = s_cr[zu] + s_cr[zv];
        const float t    = __fdividef(d, rmax);
        if (t < 1.0f) {
            const float roa = d * (s_pow[zu] + s_pow[zv]) * inv_pref;
            const float phi = s_coef[0] * __expf(-s_exp[0] * roa)
                            + s_coef[1] * __expf(-s_exp[1] * roa)
                            + s_coef[2] * __expf(-s_exp[2] * roa)
                            + s_coef[3] * __expf(-s_exp[3] * roa);
            const float v   = 14.3996f * (float)(zu * zv) * phi * __frcp_rn(d);
            const float t2  = t * t;
            const float t6  = t2 * t2 * t2;
            const float env = 1.0f - t6 * (28.0f - 48.0f * t + 21.0f * t2);
            atomicAdd(&out[rv], 0.5f * v * env);
        }
    }
}

extern "C" void kernel_launch(void* const* d_in, const int* in_sizes, int n_in,
                              void* d_out, int out_size, void* d_ws, size_t ws_size,
                              hipStream_t stream) {
    const int*   z        = (const int*)d_in[0];
    const float* dist     = (const float*)d_in[1];
    const int*   eidx     = (const int*)d_in[2];
    const float* a_factor = (const float*)d_in[3];
    const float* z_power  = (const float*)d_in[4];
    const float* coefs    = (const float*)d_in[5];
    const float* exps     = (const float*)d_in[6];
    const float* cradii   = (const float*)d_in[7];
    float* out = (float*)d_out;

    const int n_edges = in_sizes[1];
    const int*   sender   = eidx;
    const int*   receiver = eidx + n_edges;

    // zero the output accumulator every call (harness poisons once, we atomic-add)
    {
        int blocks = (out_size + 255) / 256;
        zbl_zero_kernel<<<blocks, 256, 0, stream>>>(out, out_size);
    }

    // edge kernel: 4 edges/thread, grid-stride, ~8 blocks/CU
    {
        int n_vec = n_edges >> 2;
        int blocks = (n_vec + 255) / 256;
        if (blocks > 2048) blocks = 2048;
        if (blocks < 1) blocks = 1;
        zbl_edge_kernel<<<blocks, 256, 0, stream>>>(
            z, dist, sender, receiver, a_factor, z_power, coefs, exps, cradii,
            out, n_edges);
    }
}

// Round 2
// 165.636 us; speedup vs baseline: 1.0108x; 1.0108x over previous
//
#include <hip/hip_runtime.h>

#define N_ELEM 95

__global__ void zbl_zero_kernel(float* __restrict__ p, int n) {
    int i = blockIdx.x * blockDim.x + threadIdx.x;
    int stride = gridDim.x * blockDim.x;
    for (; i < n; i += stride) p[i] = 0.0f;
}

__global__ void zbl_reduce_kernel(const float* __restrict__ ws,
                                  float* __restrict__ out,
                                  int n_nodes, int copies) {
    int i = blockIdx.x * blockDim.x + threadIdx.x;
    if (i < n_nodes) {
        float s = 0.0f;
        for (int c = 0; c < copies; ++c) s += ws[(size_t)c * n_nodes + i];
        out[i] = s;
    }
}

__global__ __launch_bounds__(256) void zbl_edge_kernel(
    const int*   __restrict__ z,
    const float* __restrict__ dist,
    const int*   __restrict__ sender,
    const int*   __restrict__ receiver,
    const float* __restrict__ a_factor_p,
    const float* __restrict__ z_power_p,
    const float* __restrict__ coefs,
    const float* __restrict__ exps,
    const float* __restrict__ cradii,
    float*       __restrict__ outbuf,   // copies * n_nodes accumulators
    int n_edges, int n_nodes, int copy_mask)
{
    __shared__ float s_pow[N_ELEM];   // Z^Z_power table (index by atomic number)
    __shared__ float s_cr[N_ELEM];    // covalent radii
    __shared__ float s_coef[4];
    __shared__ float s_exp[4];
    __shared__ float s_inv_pref;      // 1 / (a_factor * 0.529)

    const int tid = threadIdx.x;
    if (tid < N_ELEM) {
        float zp = z_power_p[0];
        s_pow[tid] = __powf((float)tid, zp);  // tid=0 unused (z >= 1)
        s_cr[tid]  = cradii[tid];
    }
    if (tid < 4) { s_coef[tid] = coefs[tid]; s_exp[tid] = exps[tid]; }
    if (tid == 0) s_inv_pref = 1.0f / (a_factor_p[0] * 0.529f);
    __syncthreads();

    float* __restrict__ acc = outbuf + (size_t)(blockIdx.x & copy_mask) * n_nodes;

    const float inv_pref = s_inv_pref;
    const int n_vec   = n_edges >> 2;              // groups of 4 edges
    const int gstride = gridDim.x * blockDim.x;

    for (int i = blockIdx.x * blockDim.x + tid; i < n_vec; i += gstride) {
        const float4 d4 = reinterpret_cast<const float4*>(dist)[i];
        const int4   s4 = reinterpret_cast<const int4*>(sender)[i];
        const int4   r4 = reinterpret_cast<const int4*>(receiver)[i];

        float dd[4] = {d4.x, d4.y, d4.z, d4.w};
        int   ss[4] = {s4.x, s4.y, s4.z, s4.w};
        int   rr[4] = {r4.x, r4.y, r4.z, r4.w};

        #pragma unroll
        for (int k = 0; k < 4; ++k) {
            const float d  = dd[k];
            const int   zu = z[ss[k]];
            const int   zv = z[rr[k]];

            const float rmax = s_cr[zu] + s_cr[zv];
            const float t    = __fdividef(d, rmax);
            if (t < 1.0f) {
                const float roa = d * (s_pow[zu] + s_pow[zv]) * inv_pref;
                const float phi = s_coef[0] * __expf(-s_exp[0] * roa)
                                + s_coef[1] * __expf(-s_exp[1] * roa)
                                + s_coef[2] * __expf(-s_exp[2] * roa)
                                + s_coef[3] * __expf(-s_exp[3] * roa);
                const float v   = 7.1998f * (float)(zu * zv) * phi * __frcp_rn(d);
                const float t2  = t * t;
                const float t6  = t2 * t2 * t2;
                // p=6: 1 - 28 t^6 + 48 t^7 - 21 t^8
                const float env = 1.0f - t6 * (28.0f - 48.0f * t + 21.0f * t2);
                unsafeAtomicAdd(&acc[rr[k]], v * env);
            }
        }
    }

    // scalar tail (n_edges % 4)
    for (int i = (n_vec << 2) + blockIdx.x * blockDim.x + tid; i < n_edges; i += gstride) {
        const float d  = dist[i];
        const int   zu = z[sender[i]];
        const int   rv = receiver[i];
        const int   zv = z[rv];
        const float rmax = s_cr[zu] + s_cr[zv];
        const float t    = __fdividef(d, rmax);
        if (t < 1.0f) {
            const float roa = d * (s_pow[zu] + s_pow[zv]) * inv_pref;
            const float phi = s_coef[0] * __expf(-s_exp[0] * roa)
                            + s_coef[1] * __expf(-s_exp[1] * roa)
                            + s_coef[2] * __expf(-s_exp[2] * roa)
                            + s_coef[3] * __expf(-s_exp[3] * roa);
            const float v   = 7.1998f * (float)(zu * zv) * phi * __frcp_rn(d);
            const float t2  = t * t;
            const float t6  = t2 * t2 * t2;
            const float env = 1.0f - t6 * (28.0f - 48.0f * t + 21.0f * t2);
            unsafeAtomicAdd(&acc[rv], v * env);
        }
    }
}

extern "C" void kernel_launch(void* const* d_in, const int* in_sizes, int n_in,
                              void* d_out, int out_size, void* d_ws, size_t ws_size,
                              hipStream_t stream) {
    const int*   z        = (const int*)d_in[0];
    const float* dist     = (const float*)d_in[1];
    const int*   eidx     = (const int*)d_in[2];
    const float* a_factor = (const float*)d_in[3];
    const float* z_power  = (const float*)d_in[4];
    const float* coefs    = (const float*)d_in[5];
    const float* exps     = (const float*)d_in[6];
    const float* cradii   = (const float*)d_in[7];
    float* out = (float*)d_out;

    const int n_edges = in_sizes[1];
    const int n_nodes = out_size;
    const int* sender   = eidx;
    const int* receiver = eidx + n_edges;

    // how many private accumulator copies fit in the workspace? (power of 2, <=16)
    int copies = 1;
    {
        size_t max_copies = ws_size / ((size_t)n_nodes * sizeof(float));
        while (copies * 2 <= (int)max_copies && copies < 16) copies *= 2;
        if (max_copies < 1) copies = 0;  // no workspace: accumulate directly in out
    }

    const int EDGE_BLOCKS = 2048;

    if (copies >= 2) {
        float* ws = (float*)d_ws;
        int n_acc = copies * n_nodes;
        zbl_zero_kernel<<<(n_acc + 255) / 256, 256, 0, stream>>>(ws, n_acc);
        zbl_edge_kernel<<<EDGE_BLOCKS, 256, 0, stream>>>(
            z, dist, sender, receiver, a_factor, z_power, coefs, exps, cradii,
            ws, n_edges, n_nodes, copies - 1);
        zbl_reduce_kernel<<<(n_nodes + 255) / 256, 256, 0, stream>>>(
            ws, out, n_nodes, copies);
    } else {
        zbl_zero_kernel<<<(n_nodes + 255) / 256, 256, 0, stream>>>(out, n_nodes);
        zbl_edge_kernel<<<EDGE_BLOCKS, 256, 0, stream>>>(
            z, dist, sender, receiver, a_factor, z_power, coefs, exps, cradii,
            out, n_edges, n_nodes, 0);
    }
}